// Round 1
// baseline (535.936 us; speedup 1.0000x reference)
//
#include <hip/hip_runtime.h>
#include <hip/hip_bf16.h>

typedef __attribute__((ext_vector_type(8))) short bf16x8;
typedef __attribute__((ext_vector_type(4))) float f32x4;

static __device__ __forceinline__ unsigned short f2bf(float f) {
    unsigned int u = __float_as_uint(f);
    u = u + 0x7FFFu + ((u >> 16) & 1u);   // RNE; inputs are finite
    return (unsigned short)(u >> 16);
}

static __device__ __forceinline__ float fast_tanh(float x) {
    x = fminf(fmaxf(x, -10.f), 10.f);
    float e = __expf(2.f * x);
    return __fdividef(e - 1.f, e + 1.f);
}

// ---------------- generic small fp32 GEMM: C[m][n] = sum_k A[m][k]*W[n*ldw+woff+k] + bias[n]
// M fixed at 384 (grid.x = 6), 64x64 tile, 256 threads, 4x4 per thread.
__global__ __launch_bounds__(256)
void sgemm_bt(const float* __restrict__ A, const float* __restrict__ W,
              const float* __restrict__ bias, float* __restrict__ C,
              int N, int K, int ldw, int woff)
{
    __shared__ float As[64][33];
    __shared__ float Ws[64][33];
    const int tid = threadIdx.x;
    const int tx = tid & 15, ty = tid >> 4;
    const int m0 = blockIdx.x * 64, n0 = blockIdx.y * 64;
    const int kc = tid & 31;
    const int r0 = tid >> 5;
    float acc[4][4] = {};
    for (int k0 = 0; k0 < K; k0 += 32) {
        #pragma unroll
        for (int i = 0; i < 8; ++i) {
            int row = r0 + i * 8;
            As[row][kc] = A[(m0 + row) * K + k0 + kc];
            int n = n0 + row;
            Ws[row][kc] = (n < N) ? W[(long)n * ldw + woff + k0 + kc] : 0.f;
        }
        __syncthreads();
        #pragma unroll
        for (int kk = 0; kk < 32; ++kk) {
            float a[4], w[4];
            #pragma unroll
            for (int i = 0; i < 4; ++i) a[i] = As[ty * 4 + i][kk];
            #pragma unroll
            for (int j = 0; j < 4; ++j) w[j] = Ws[tx * 4 + j][kk];
            #pragma unroll
            for (int i = 0; i < 4; ++i)
                #pragma unroll
                for (int j = 0; j < 4; ++j) acc[i][j] += a[i] * w[j];
        }
        __syncthreads();
    }
    #pragma unroll
    for (int i = 0; i < 4; ++i) {
        int m = m0 + ty * 4 + i;
        #pragma unroll
        for (int j = 0; j < 4; ++j) {
            int n = n0 + tx * 4 + j;
            if (n < N) C[m * N + n] = acc[i][j] + (bias ? bias[n] : 0.f);
        }
    }
}

// ---------------- attention: one block per (row n, head h). 8 heads, HEAD_D=32.
__global__ __launch_bounds__(256)
void attn_kernel(const float* __restrict__ qkv, float* __restrict__ out)
{
    const int n = blockIdx.x;
    const int h = blockIdx.y;
    const int tid = threadIdx.x;
    const int lane = tid & 63;
    const int wid = tid >> 6;

    __shared__ float qs[32];
    __shared__ float p[384];
    __shared__ float red[8];
    __shared__ float pv[8][32];

    if (tid < 32) qs[tid] = qkv[n * 768 + h * 32 + tid] * 0.17677669529663687f; // /sqrt(32)
    __syncthreads();

    float lmax = -1e30f;
    for (int m = tid; m < 384; m += 256) {
        const float4* kr = (const float4*)(qkv + m * 768 + 256 + h * 32);
        float s = 0.f;
        #pragma unroll
        for (int d = 0; d < 8; ++d) {
            float4 kv = kr[d];
            s += qs[d*4+0]*kv.x + qs[d*4+1]*kv.y + qs[d*4+2]*kv.z + qs[d*4+3]*kv.w;
        }
        p[m] = s;
        lmax = fmaxf(lmax, s);
    }
    #pragma unroll
    for (int off = 32; off >= 1; off >>= 1) lmax = fmaxf(lmax, __shfl_xor(lmax, off));
    if (lane == 0) red[wid] = lmax;
    __syncthreads();
    const float gmax = fmaxf(fmaxf(red[0], red[1]), fmaxf(red[2], red[3]));

    float lsum = 0.f;
    for (int m = tid; m < 384; m += 256) {
        float e = __expf(p[m] - gmax);
        p[m] = e;
        lsum += e;
    }
    #pragma unroll
    for (int off = 32; off >= 1; off >>= 1) lsum += __shfl_xor(lsum, off);
    if (lane == 0) red[4 + wid] = lsum;
    __syncthreads();
    const float inv = 1.f / (red[4] + red[5] + red[6] + red[7]);

    const int d = tid & 31;
    const int g = tid >> 5;
    float acc = 0.f;
    for (int m = g * 48; m < g * 48 + 48; ++m)
        acc += p[m] * qkv[m * 768 + 512 + h * 32 + d];
    pv[g][d] = acc;
    __syncthreads();
    if (tid < 32) {
        float o = 0.f;
        #pragma unroll
        for (int gg = 0; gg < 8; ++gg) o += pv[gg][tid];
        out[n * 256 + h * 32 + tid] = o * inv;
    }
}

// ---------------- scatter node -> W0 / B0 / W1 regions of d_out
__global__ void scatter_node(const float* __restrict__ node, float* __restrict__ out)
{
    int i = blockIdx.x * 256 + threadIdx.x;      // exactly 384*80 = 30720 threads
    int n = i / 80, c = i - n * 80;
    float v = node[i];
    if (c < 64)      out[117964800 + n * 64 + c] = v;
    else if (c < 72) out[117989376 + n * 8 + (c - 64)] = v;
    else             out[117992448 + n * 8 + (c - 72)] = v;
}

// ---------------- fci_w2 fp32 -> bf16 (row-major [800][256])
__global__ void conv_w2(const float* __restrict__ w, unsigned short* __restrict__ o)
{
    int i = blockIdx.x * 256 + threadIdx.x;      // exactly 800*256 = 204800
    o[i] = f2bf(w[i]);
}

// ---------------- the big fused kernel: per (i,j): t = tanh(hA[j]+hB[i]) (b1 folded into hA)
// K[i,j,:] | Q[i,j,:] = t @ w2^T + b2.   M=147456, K=256, N=800.
#define BM 128
#define BN 160
#define KD 256

__global__ __launch_bounds__(512, 2)
void gen_kq(const float* __restrict__ hA, const float* __restrict__ hB,
            const unsigned short* __restrict__ w2b, const float* __restrict__ b2,
            float* __restrict__ outK, float* __restrict__ outQ)
{
    __shared__ unsigned char As[BM * KD * 2];  // 64 KB, bf16, XOR-swizzled
    __shared__ unsigned char Bs[BN * KD * 2];  // 80 KB, bf16, XOR-swizzled

    const int tid   = threadIdx.x;
    const int mtile = blockIdx.x;
    const int ntile = blockIdx.y;
    const int m0    = mtile * BM;
    const int ai    = m0 / 384;        // constant per tile: 384 = 3*128
    const int bj0   = m0 - ai * 384;

    // ---- stage A: tanh(hA[j] + hB[ai]) -> bf16 LDS, swizzle byte ^= (row&7)<<4
    {
        const int kc = tid & 31;
        const int k  = kc << 3;
        const float4* hb = (const float4*)(hB + ai * 256 + k);
        const float4 c0 = hb[0], c1 = hb[1];
        int row = tid >> 5;
        #pragma unroll
        for (int it = 0; it < 8; ++it, row += 16) {
            const float4* pa = (const float4*)(hA + (bj0 + row) * 256 + k);
            float4 a0 = pa[0], a1 = pa[1];
            float t0 = fast_tanh(a0.x + c0.x);
            float t1 = fast_tanh(a0.y + c0.y);
            float t2 = fast_tanh(a0.z + c0.z);
            float t3 = fast_tanh(a0.w + c0.w);
            float t4 = fast_tanh(a1.x + c1.x);
            float t5 = fast_tanh(a1.y + c1.y);
            float t6 = fast_tanh(a1.z + c1.z);
            float t7 = fast_tanh(a1.w + c1.w);
            uint4 pk;
            pk.x = (unsigned)f2bf(t0) | ((unsigned)f2bf(t1) << 16);
            pk.y = (unsigned)f2bf(t2) | ((unsigned)f2bf(t3) << 16);
            pk.z = (unsigned)f2bf(t4) | ((unsigned)f2bf(t5) << 16);
            pk.w = (unsigned)f2bf(t6) | ((unsigned)f2bf(t7) << 16);
            int byte = (row << 9) + ((k << 1) ^ ((row & 7) << 4));
            *(uint4*)(As + byte) = pk;
        }
    }
    // ---- stage B: w2 bf16 rows [ntile*160 .. +160), same swizzle
    {
        const int kc = tid & 31;
        const int k  = kc << 3;
        int r = tid >> 5;
        #pragma unroll
        for (int it = 0; it < 10; ++it, r += 16) {
            uint4 v = *(const uint4*)(w2b + (size_t)(ntile * BN + r) * 256 + k);
            int byte = (r << 9) + ((k << 1) ^ ((r & 7) << 4));
            *(uint4*)(Bs + byte) = v;
        }
    }
    __syncthreads();

    // ---- compute: 8 waves, 4(M) x 2(N); per-wave 32x80 = 2x5 fragments
    const int lane = tid & 63;
    const int wid  = tid >> 6;
    const int wm   = wid >> 1;
    const int wn   = wid & 1;
    const int lr   = lane & 15;

    f32x4 acc[2][5];
    #pragma unroll
    for (int i = 0; i < 2; ++i)
        #pragma unroll
        for (int j = 0; j < 5; ++j)
            acc[i][j] = (f32x4){0.f, 0.f, 0.f, 0.f};

    int arow[2];
    arow[0] = wm * 32 + lr;
    arow[1] = arow[0] + 16;
    int brow[5];
    #pragma unroll
    for (int j = 0; j < 5; ++j) brow[j] = wn * 80 + j * 16 + lr;

    #pragma unroll
    for (int kk = 0; kk < 8; ++kk) {
        const int kb = kk * 64 + ((lane >> 4) << 4);   // byte offset of this lane's 8 bf16
        bf16x8 af[2], bfr[5];
        #pragma unroll
        for (int i = 0; i < 2; ++i) {
            int r = arow[i];
            af[i] = *(const bf16x8*)(As + (r << 9) + (kb ^ ((r & 7) << 4)));
        }
        #pragma unroll
        for (int j = 0; j < 5; ++j) {
            int r = brow[j];
            bfr[j] = *(const bf16x8*)(Bs + (r << 9) + (kb ^ ((r & 7) << 4)));
        }
        #pragma unroll
        for (int i = 0; i < 2; ++i)
            #pragma unroll
            for (int j = 0; j < 5; ++j)
                acc[i][j] = __builtin_amdgcn_mfma_f32_16x16x32_bf16(af[i], bfr[j], acc[i][j], 0, 0, 0);
    }

    // ---- epilogue: C/D layout col = lane&15, row = (lane>>4)*4 + reg
    const int rr = (lane >> 4) << 2;
    #pragma unroll
    for (int j = 0; j < 5; ++j) {
        const int col = ntile * BN + wn * 80 + j * 16 + lr;
        const float bias = b2[col];
        float* base = (col < 400) ? (outK + col) : (outQ + (col - 400));
        #pragma unroll
        for (int i = 0; i < 2; ++i) {
            #pragma unroll
            for (int rg = 0; rg < 4; ++rg) {
                const long m = (long)(m0 + wm * 32 + i * 16 + rr + rg);
                base[m * 400] = acc[i][j][rg] + bias;
            }
        }
    }
}

extern "C" void kernel_launch(void* const* d_in, const int* in_sizes, int n_in,
                              void* d_out, int out_size, void* d_ws, size_t ws_size,
                              hipStream_t stream)
{
    (void)in_sizes; (void)n_in; (void)out_size; (void)ws_size;

    const float* h      = (const float*)d_in[0];
    const float* fc_w   = (const float*)d_in[1];
    const float* fc_b   = (const float*)d_in[2];
    const float* inp_w  = (const float*)d_in[3];
    const float* inp_b  = (const float*)d_in[4];
    const float* outp_w = (const float*)d_in[5];
    const float* outp_b = (const float*)d_in[6];
    const float* fci_w1 = (const float*)d_in[7];
    const float* fci_b1 = (const float*)d_in[8];
    const float* fci_w2 = (const float*)d_in[9];
    const float* fci_b2 = (const float*)d_in[10];
    const float* fcn_w  = (const float*)d_in[11];
    const float* fcn_b  = (const float*)d_in[12];

    float* out  = (float*)d_out;
    float* outK = out;
    float* outQ = out + 58982400;   // 384*384*400

    float* ws   = (float*)d_ws;
    float* h1   = ws;                    // 384*256
    float* qkv  = h1   + 384 * 256;      // 384*768
    float* attn = qkv  + 384 * 768;      // 384*256
    float* h2   = attn + 384 * 256;      // 384*256
    float* hA   = h2   + 384 * 256;      // 384*256  (b1 folded in)
    float* hBv  = hA   + 384 * 256;      // 384*256
    float* node = hBv  + 384 * 256;      // 384*80
    unsigned short* w2b = (unsigned short*)(node + 384 * 80); // 800*256 bf16

    // Phase A (fp32)
    sgemm_bt<<<dim3(6, 4),  256, 0, stream>>>(h,    fc_w,   fc_b,   h1,   256, 128, 128, 0);
    sgemm_bt<<<dim3(6, 12), 256, 0, stream>>>(h1,   inp_w,  inp_b,  qkv,  768, 256, 256, 0);
    attn_kernel<<<dim3(384, 8), 256, 0, stream>>>(qkv, attn);
    sgemm_bt<<<dim3(6, 4),  256, 0, stream>>>(attn, outp_w, outp_b, h2,   256, 256, 256, 0);
    sgemm_bt<<<dim3(6, 4),  256, 0, stream>>>(h2,   fci_w1, fci_b1, hA,   256, 256, 512, 0);
    sgemm_bt<<<dim3(6, 4),  256, 0, stream>>>(h2,   fci_w1, nullptr, hBv, 256, 256, 512, 256);
    sgemm_bt<<<dim3(6, 2),  256, 0, stream>>>(h2,   fcn_w,  fcn_b,  node, 80,  256, 256, 0);
    scatter_node<<<120, 256, 0, stream>>>(node, out);
    conv_w2<<<800, 256, 0, stream>>>(fci_w2, w2b);

    // Phase B (bf16 MFMA)
    gen_kq<<<dim3(1152, 5), 512, 0, stream>>>(hA, hBv, w2b, fci_b2, outK, outQ);
}